// Round 18
// baseline (267.866 us; speedup 1.0000x reference)
//
#include <hip/hip_runtime.h>
#include <hip/hip_bf16.h>

#define N_NODES 50000
#define N_EDGES 800000
#define D_IN    512
#define D_OUT   256
#define NBLK_SCAN ((N_NODES + 1023) / 1024)   // 49
#define GEMM_NWG (((N_NODES + 127) / 128) * 2)  // 782
#define GEMM_Q   (GEMM_NWG / 8)                  // 97
#define GEMM_R   (GEMM_NWG % 8)                  // 6

typedef short s8v  __attribute__((ext_vector_type(8)));
typedef float f32x4 __attribute__((ext_vector_type(4)));

__device__ __forceinline__ unsigned short bf16b(float f) {
    __hip_bfloat16 h = __float2bfloat16(f);
    return *reinterpret_cast<unsigned short*>(&h);
}
__device__ __forceinline__ float bflo(unsigned u) { return __uint_as_float(u << 16); }
__device__ __forceinline__ float bfhi(unsigned u) { return __uint_as_float(u & 0xffff0000u); }

// global -> LDS direct copy, 16B per lane; LDS dest arg = wave-uniform base,
// HW adds lane*16.
#define GLD16(gp, lp)                                                           \
    __builtin_amdgcn_global_load_lds(                                           \
        (const __attribute__((address_space(1))) unsigned int*)(const void*)(gp),\
        (__attribute__((address_space(3))) unsigned int*)(void*)(lp), 16, 0, 0)

__device__ __forceinline__ int wave_incl_scan(int v, int lane) {
    #pragma unroll
    for (int d = 1; d < 64; d <<= 1) {
        int u = __shfl_up(v, d, 64);
        if (lane >= d) v += u;
    }
    return v;
}

// ============ W transpose + bf16 convert; also zeroes cnt4 (saves a memset) ===
__global__ void k_wt(const float* __restrict__ W, unsigned short* __restrict__ Wt,
                     int* __restrict__ cnt4) {
    int k = blockIdx.x;      // 512
    int n = threadIdx.x;     // 256
    Wt[(size_t)n * D_IN + k] = bf16b(W[(size_t)k * D_OUT + n]);
    int t = (blockIdx.x * 256 + threadIdx.x) * 2;     // 262144 slots >= 200000
    if (t < 4 * N_NODES) {
        cnt4[t] = 0;
        if (t + 1 < 4 * N_NODES) cnt4[t + 1] = 0;
    }
}

// ============ CSR build (4-way replicated counters) ============

__global__ void k_count(const int* __restrict__ col, int* __restrict__ cnt4) {
    int i = (blockIdx.x * 256 + threadIdx.x) * 2;
    if (i < N_EDGES) {                            // N_EDGES even; i even
        int2 c = *(const int2*)&col[i];
        atomicAdd(&cnt4[(i & 3) * N_NODES + c.x], 1);
        atomicAdd(&cnt4[((i + 1) & 3) * N_NODES + c.y], 1);
    }
}

__launch_bounds__(256)
__global__ void k_scan1(const int* __restrict__ cnt4, int* __restrict__ bsum) {
    const int t = threadIdx.x, b = blockIdx.x;
    const int idx = b * 1024 + t * 4;
    int s = 0;
    if (idx < N_NODES) {
        #pragma unroll
        for (int q = 0; q < 4; ++q) {
            int4 v = *(const int4*)&cnt4[q * N_NODES + idx];
            s += (v.x + v.y) + (v.z + v.w);
        }
    }
    #pragma unroll
    for (int d = 1; d < 64; d <<= 1) s += __shfl_xor(s, d, 64);
    __shared__ int ws[4];
    if ((t & 63) == 0) ws[t >> 6] = s;
    __syncthreads();
    if (t == 0) bsum[b] = ws[0] + ws[1] + ws[2] + ws[3];
}

// in-block exclusive scan + self-computed block offset; emits row_ptr, dinv,
// and EXACT per-replica cursor bases cursor4[q*N+c] = row_ptr[c]+prefix_q
__launch_bounds__(256)
__global__ void k_scan3(const int* __restrict__ cnt4, const int* __restrict__ bsum,
                        int* __restrict__ row_ptr, float* __restrict__ dinv,
                        int* __restrict__ cursor4) {
    const int t = threadIdx.x, b = blockIdx.x;
    const int lane = t & 63, wv = t >> 6;
    const int idx = b * 1024 + t * 4;
    int4 vq[4];
    int4 tot = make_int4(0, 0, 0, 0);
    if (idx < N_NODES) {
        #pragma unroll
        for (int q = 0; q < 4; ++q) {
            vq[q] = *(const int4*)&cnt4[q * N_NODES + idx];
            tot.x += vq[q].x; tot.y += vq[q].y;
            tot.z += vq[q].z; tot.w += vq[q].w;
        }
    } else {
        #pragma unroll
        for (int q = 0; q < 4; ++q) vq[q] = make_int4(0, 0, 0, 0);
    }
    int s = (tot.x + tot.y) + (tot.z + tot.w);
    int isc = wave_incl_scan(s, lane);
    __shared__ int wsum[4];
    __shared__ int s_boff;
    if (lane == 63) wsum[wv] = isc;
    if (t < 64) {                                  // wave 0: sum of bsum[0..b)
        int u = (t < b) ? bsum[t] : 0;             // b <= 48 < 64
        #pragma unroll
        for (int d = 1; d < 64; d <<= 1) u += __shfl_xor(u, d, 64);
        if (t == 0) s_boff = u;
    }
    __syncthreads();
    int off = s_boff;
    #pragma unroll
    for (int i = 0; i < 4; ++i)
        if (i < wv) off += wsum[i];
    int p0 = off + isc - s;
    int p1 = p0 + tot.x;
    int p2 = p1 + tot.y;
    int p3 = p2 + tot.z;
    if (idx < N_NODES) {
        row_ptr[idx + 0] = p0; dinv[idx + 0] = rsqrtf(1.f + (float)tot.x);
        row_ptr[idx + 1] = p1; dinv[idx + 1] = rsqrtf(1.f + (float)tot.y);
        row_ptr[idx + 2] = p2; dinv[idx + 2] = rsqrtf(1.f + (float)tot.z);
        row_ptr[idx + 3] = p3; dinv[idx + 3] = rsqrtf(1.f + (float)tot.w);
        int4 run = make_int4(p0, p1, p2, p3);
        #pragma unroll
        for (int q = 0; q < 4; ++q) {
            *(int4*)&cursor4[q * N_NODES + idx] = run;
            run.x += vq[q].x; run.y += vq[q].y;
            run.z += vq[q].z; run.w += vq[q].w;
        }
    }
    if (b == 0 && t == 0) row_ptr[N_NODES] = N_EDGES;
}

__global__ void k_fill(const int* __restrict__ row, const int* __restrict__ col,
                       int* __restrict__ cursor4, int* __restrict__ csr_src) {
    int i = (blockIdx.x * 256 + threadIdx.x) * 2;
    if (i < N_EDGES) {
        int2 c = *(const int2*)&col[i];
        int2 r = *(const int2*)&row[i];
        int p0 = atomicAdd(&cursor4[(i & 3) * N_NODES + c.x], 1);
        csr_src[p0] = r.x;
        int p1 = atomicAdd(&cursor4[((i + 1) & 3) * N_NODES + c.y], 1);
        csr_src[p1] = r.y;
    }
}

// ============ MFMA GEMM: yb_blk = bf16(dinv[r] * (x @ W)), COLUMN-BLOCKED ====
__launch_bounds__(256)
__global__ void k_gemm(const float* __restrict__ A,            // [N_NODES,512] fp32
                       const unsigned short* __restrict__ Wt,  // [256,512] bf16
                       const float* __restrict__ dinv,
                       unsigned short* __restrict__ yb)        // [8][N_NODES][32] bf16
{
    __shared__ __align__(16) float          As[128 * 64];   // 32 KB, [m][64k] fp32
    __shared__ __align__(16) unsigned short Bs[128 * 64];   // 16 KB, [n][64k] bf16

    // bijective XCD swizzle (m204)
    int orig = blockIdx.x;
    int xcd = orig % 8, pos = orig / 8;
    int wg = (xcd < GEMM_R) ? xcd * (GEMM_Q + 1) + pos
                            : GEMM_R * (GEMM_Q + 1) + (xcd - GEMM_R) * GEMM_Q + pos;
    const int nt = wg & 1;
    const int mt = wg >> 1;
    const int m0 = mt * 128;
    const int n0 = nt * 128;

    const int t  = threadIdx.x;
    const int w  = t >> 6;
    const int l  = t & 63;
    const int wm = (w >> 1) * 64;
    const int wn = (w & 1) * 64;
    const int lr = l & 15;
    const int lk = l >> 4;

    size_t aoff[8];
    #pragma unroll
    for (int i = 0; i < 8; ++i) {
        int row = m0 + w * 32 + i * 4 + (l >> 4);
        if (row >= N_NODES) row = 0;             // tail clamp; outputs guarded
        int sslot = (l & 15) ^ (row & 7);
        aoff[i] = (size_t)row * D_IN + sslot * 4;   // float units
    }
    const int srow = l >> 3;
    const int srcj = (l & 7) ^ srow;
    size_t boff[4];
    #pragma unroll
    for (int i = 0; i < 4; ++i) {
        int g = w * 4 + i;
        int bn = n0 + g * 8 + srow;
        boff[i] = (size_t)bn * D_IN + srcj * 8;
    }

    f32x4 acc[4][4] = {};

    for (int kk = 0; kk < D_IN; kk += 64) {
        #pragma unroll
        for (int i = 0; i < 8; ++i)
            GLD16(&A[aoff[i] + kk], (char*)As + (w * 32 + i * 4) * 256);
        #pragma unroll
        for (int i = 0; i < 4; ++i)
            GLD16(&Wt[boff[i] + kk], (char*)Bs + (w * 4 + i) * 1024);
        __syncthreads();

        #pragma unroll
        for (int ks = 0; ks < 2; ++ks) {
            s8v af[4], bfr[4];
            #pragma unroll
            for (int f = 0; f < 4; ++f) {
                int row = wm + f * 16 + lr;           // row&7 == lr&7
                int a   = (ks * 4 + lk) * 2;          // logical 16B slot (even)
                int s0  = a ^ (lr & 7);
                int s1  = (a + 1) ^ (lr & 7);         // = s0 ^ 1
                const char* pr = (const char*)As + row * 256;
                float4 x0 = *(const float4*)(pr + s0 * 16);
                float4 x1 = *(const float4*)(pr + s1 * 16);
                union { s8v v; unsigned short h[8]; } u;
                u.h[0] = bf16b(x0.x); u.h[1] = bf16b(x0.y);
                u.h[2] = bf16b(x0.z); u.h[3] = bf16b(x0.w);
                u.h[4] = bf16b(x1.x); u.h[5] = bf16b(x1.y);
                u.h[6] = bf16b(x1.z); u.h[7] = bf16b(x1.w);
                af[f] = u.v;
            }
            const int kb = (ks * 64 + lk * 16) ^ ((lr & 7) << 4);
            #pragma unroll
            for (int f = 0; f < 4; ++f)
                bfr[f] = *(const s8v*)((const char*)Bs + ((wn + f * 16 + lr) * 128 + kb));
            #pragma unroll
            for (int fm = 0; fm < 4; ++fm)
                #pragma unroll
                for (int fn = 0; fn < 4; ++fn)
                    acc[fm][fn] = __builtin_amdgcn_mfma_f32_16x16x32_bf16(
                        af[fm], bfr[fn], acc[fm][fn], 0, 0, 0);
        }
        __syncthreads();
    }

    #pragma unroll
    for (int fm = 0; fm < 4; ++fm) {
        #pragma unroll
        for (int j = 0; j < 4; ++j) {
            int row = m0 + wm + fm * 16 + lk * 4 + j;
            if (row < N_NODES) {
                float s = dinv[row];
                #pragma unroll
                for (int fn = 0; fn < 4; ++fn) {
                    int col = n0 + wn + fn * 16 + lr;
                    size_t off = (size_t)(col >> 5) * (N_NODES * 32)
                               + (size_t)row * 32 + (col & 31);
                    yb[off] = bf16b(acc[fm][fn][j] * s);
                }
            }
        }
    }
}

// ============ gather (wave-per-target-slice, 16 edges in flight) ============
// R17 lesson: multi-target groups diverge and drop occupancy. Here ONE WAVE
// owns one (target, slice): 16 edge-slots x 4 col-lanes. One wave value-load
// = 16 edges; loop bound is wave-UNIFORM; idx loads are 64B contiguous and
// prefetched one round ahead; fixed 4-step shfl_xor tree combines slots once
// at the end. VGPR ~32 -> high occupancy.
__device__ __forceinline__ void add8(float* acc, uint4 q) {
    unsigned x;
    x = q.x; acc[0] += bflo(x); acc[1] += bfhi(x);
    x = q.y; acc[2] += bflo(x); acc[3] += bfhi(x);
    x = q.z; acc[4] += bflo(x); acc[5] += bfhi(x);
    x = q.w; acc[6] += bflo(x); acc[7] += bfhi(x);
}

__launch_bounds__(256)
__global__ void k_gather(const int* __restrict__ row_ptr, const int* __restrict__ csr_src,
                         const unsigned short* __restrict__ yb,   // [8][N_NODES][32]
                         const float* __restrict__ dinv,
                         const float* __restrict__ bias, float* __restrict__ out)
{
    const int s    = blockIdx.x & 7;           // slice -> XCD (dispatch %8)
    const int c    = (blockIdx.x >> 3) * 4 + (threadIdx.x >> 6);   // exact: 12500*4=50000
    const int l    = threadIdx.x & 63;
    const int slot = l >> 2;                   // edge-slot 0..15
    const int cs   = l & 3;                    // 16B col-slot within slice

    const uint4* t4 = (const uint4*)(yb + (size_t)s * N_NODES * 32);  // 4 uint4/node

    const int e0 = row_ptr[c];
    const int e1 = row_ptr[c + 1];

    uint4 sv = t4[(size_t)c * 4 + cs];         // self-loop term (issued early)

    float acc[8] = {0.f,0.f,0.f,0.f,0.f,0.f,0.f,0.f};

    int i = e0;
    int idx = 0;
    if (e1 > e0) {
        int p = e0 + slot;
        idx = csr_src[p < e1 ? p : e1 - 1];
    }
    while (i < e1) {                           // wave-uniform loop
        uint4 v = t4[(size_t)idx * 4 + cs];    // 16 edges in one wave-load
        int ni = i + 16;
        int np = ni + slot;
        int nidx = csr_src[np < e1 ? np : e1 - 1];   // prefetch next round
        if (i + slot < e1) add8(acc, v);       // lane predicate (exec mask)
        i = ni;
        idx = nidx;
    }
    if (slot == 0) add8(acc, sv);

    // combine the 16 edge-slots (lanes with same cs differ in bits 2..5)
    #pragma unroll
    for (int d = 4; d < 64; d <<= 1)
        #pragma unroll
        for (int u = 0; u < 8; ++u)
            acc[u] += __shfl_xor(acc[u], d, 64);

    if (slot == 0) {
        const float sc = dinv[c];
        const int colb = s * 32 + cs * 8;
        float4 b0 = *(const float4*)&bias[colb];
        float4 b1 = *(const float4*)&bias[colb + 4];
        float4 o0, o1;
        o0.x = fmaxf(fmaf(acc[0], sc, b0.x), 0.f);
        o0.y = fmaxf(fmaf(acc[1], sc, b0.y), 0.f);
        o0.z = fmaxf(fmaf(acc[2], sc, b0.z), 0.f);
        o0.w = fmaxf(fmaf(acc[3], sc, b0.w), 0.f);
        o1.x = fmaxf(fmaf(acc[4], sc, b1.x), 0.f);
        o1.y = fmaxf(fmaf(acc[5], sc, b1.y), 0.f);
        o1.z = fmaxf(fmaf(acc[6], sc, b1.z), 0.f);
        o1.w = fmaxf(fmaf(acc[7], sc, b1.w), 0.f);
        float* dst = &out[(size_t)c * D_OUT + colb];
        *(float4*)dst       = o0;
        *(float4*)(dst + 4) = o1;
    }
}

extern "C" void kernel_launch(void* const* d_in, const int* in_sizes, int n_in,
                              void* d_out, int out_size, void* d_ws, size_t ws_size,
                              hipStream_t stream) {
    const float* x   = (const float*)d_in[0];
    const int*   ei  = (const int*)d_in[1];
    const float* W   = (const float*)d_in[2];
    const float* b   = (const float*)d_in[3];
    float*       out = (float*)d_out;

    const int* row = ei;
    const int* col = ei + N_EDGES;

    char* p = (char*)d_ws;
    unsigned short* yb = (unsigned short*)p;  p += (size_t)N_NODES * D_OUT * 2;   // 25.6 MB
    unsigned short* Wt = (unsigned short*)p;  p += (size_t)D_OUT * D_IN * 2;      // 256 KB
    int*   csr_src = (int*)p;                 p += (size_t)N_EDGES * 4;           // 3.2 MB
    int*   cnt4    = (int*)p;                 p += (size_t)4 * N_NODES * 4;       // 800 KB
    int*   row_ptr = (int*)p;                 p += (size_t)(N_NODES + 4) * 4;
    int*   cursor4 = (int*)p;                 p += (size_t)4 * N_NODES * 4;       // 800 KB
    float* dinv    = (float*)p;               p += (size_t)N_NODES * 4;
    int*   bsum    = (int*)p;                 p += (size_t)NBLK_SCAN * 4;

    k_wt   <<<D_IN, D_OUT, 0, stream>>>(W, Wt, cnt4);   // also zeroes cnt4
    k_count<<<(N_EDGES / 2 + 255) / 256, 256, 0, stream>>>(col, cnt4);
    k_scan1<<<NBLK_SCAN, 256, 0, stream>>>(cnt4, bsum);
    k_scan3<<<NBLK_SCAN, 256, 0, stream>>>(cnt4, bsum, row_ptr, dinv, cursor4);
    k_fill <<<(N_EDGES / 2 + 255) / 256, 256, 0, stream>>>(row, col, cursor4, csr_src);

    k_gemm<<<GEMM_NWG, 256, 0, stream>>>(x, Wt, dinv, yb);

    k_gather<<<(N_NODES / 4) * 8, 256, 0, stream>>>(row_ptr, csr_src, yb, dinv, b, out);
}

// Round 19
// 193.138 us; speedup vs baseline: 1.3869x; 1.3869x over previous
//
#include <hip/hip_runtime.h>
#include <hip/hip_bf16.h>

#define N_NODES 50000
#define N_EDGES 800000
#define D_IN    512
#define D_OUT   256
#define NBLK_SCAN ((N_NODES + 1023) / 1024)   // 49
#define GEMM_NWG (((N_NODES + 127) / 128) * 2)  // 782
#define GEMM_Q   (GEMM_NWG / 8)                  // 97
#define GEMM_R   (GEMM_NWG % 8)                  // 6
#define GATH_CHUNKS ((N_NODES + 63) / 64)        // 782

typedef short s8v  __attribute__((ext_vector_type(8)));
typedef float f32x4 __attribute__((ext_vector_type(4)));

__device__ __forceinline__ unsigned short bf16b(float f) {
    __hip_bfloat16 h = __float2bfloat16(f);
    return *reinterpret_cast<unsigned short*>(&h);
}
__device__ __forceinline__ float bflo(unsigned u) { return __uint_as_float(u << 16); }
__device__ __forceinline__ float bfhi(unsigned u) { return __uint_as_float(u & 0xffff0000u); }

// global -> LDS direct copy, 16B per lane; LDS dest arg = wave-uniform base,
// HW adds lane*16.
#define GLD16(gp, lp)                                                           \
    __builtin_amdgcn_global_load_lds(                                           \
        (const __attribute__((address_space(1))) unsigned int*)(const void*)(gp),\
        (__attribute__((address_space(3))) unsigned int*)(void*)(lp), 16, 0, 0)

__device__ __forceinline__ int wave_incl_scan(int v, int lane) {
    #pragma unroll
    for (int d = 1; d < 64; d <<= 1) {
        int u = __shfl_up(v, d, 64);
        if (lane >= d) v += u;
    }
    return v;
}

// ============ W transpose + bf16 convert; also zeroes cnt4 (saves a memset) ===
__global__ void k_wt(const float* __restrict__ W, unsigned short* __restrict__ Wt,
                     int* __restrict__ cnt4) {
    int k = blockIdx.x;      // 512
    int n = threadIdx.x;     // 256
    Wt[(size_t)n * D_IN + k] = bf16b(W[(size_t)k * D_OUT + n]);
    int t = (blockIdx.x * 256 + threadIdx.x) * 2;     // 262144 slots >= 200000
    if (t < 4 * N_NODES) {
        cnt4[t] = 0;
        if (t + 1 < 4 * N_NODES) cnt4[t + 1] = 0;
    }
}

// ============ CSR build (4-way replicated counters) ============

__global__ void k_count(const int* __restrict__ col, int* __restrict__ cnt4) {
    int i = (blockIdx.x * 256 + threadIdx.x) * 2;
    if (i < N_EDGES) {                            // N_EDGES even; i even
        int2 c = *(const int2*)&col[i];
        atomicAdd(&cnt4[(i & 3) * N_NODES + c.x], 1);
        atomicAdd(&cnt4[((i + 1) & 3) * N_NODES + c.y], 1);
    }
}

__launch_bounds__(256)
__global__ void k_scan1(const int* __restrict__ cnt4, int* __restrict__ bsum) {
    const int t = threadIdx.x, b = blockIdx.x;
    const int idx = b * 1024 + t * 4;
    int s = 0;
    if (idx < N_NODES) {
        #pragma unroll
        for (int q = 0; q < 4; ++q) {
            int4 v = *(const int4*)&cnt4[q * N_NODES + idx];
            s += (v.x + v.y) + (v.z + v.w);
        }
    }
    #pragma unroll
    for (int d = 1; d < 64; d <<= 1) s += __shfl_xor(s, d, 64);
    __shared__ int ws[4];
    if ((t & 63) == 0) ws[t >> 6] = s;
    __syncthreads();
    if (t == 0) bsum[b] = ws[0] + ws[1] + ws[2] + ws[3];
}

// in-block exclusive scan + self-computed block offset; emits row_ptr, dinv,
// and EXACT per-replica cursor bases cursor4[q*N+c] = row_ptr[c]+prefix_q
__launch_bounds__(256)
__global__ void k_scan3(const int* __restrict__ cnt4, const int* __restrict__ bsum,
                        int* __restrict__ row_ptr, float* __restrict__ dinv,
                        int* __restrict__ cursor4) {
    const int t = threadIdx.x, b = blockIdx.x;
    const int lane = t & 63, wv = t >> 6;
    const int idx = b * 1024 + t * 4;
    int4 vq[4];
    int4 tot = make_int4(0, 0, 0, 0);
    if (idx < N_NODES) {
        #pragma unroll
        for (int q = 0; q < 4; ++q) {
            vq[q] = *(const int4*)&cnt4[q * N_NODES + idx];
            tot.x += vq[q].x; tot.y += vq[q].y;
            tot.z += vq[q].z; tot.w += vq[q].w;
        }
    } else {
        #pragma unroll
        for (int q = 0; q < 4; ++q) vq[q] = make_int4(0, 0, 0, 0);
    }
    int s = (tot.x + tot.y) + (tot.z + tot.w);
    int isc = wave_incl_scan(s, lane);
    __shared__ int wsum[4];
    __shared__ int s_boff;
    if (lane == 63) wsum[wv] = isc;
    if (t < 64) {                                  // wave 0: sum of bsum[0..b)
        int u = (t < b) ? bsum[t] : 0;             // b <= 48 < 64
        #pragma unroll
        for (int d = 1; d < 64; d <<= 1) u += __shfl_xor(u, d, 64);
        if (t == 0) s_boff = u;
    }
    __syncthreads();
    int off = s_boff;
    #pragma unroll
    for (int i = 0; i < 4; ++i)
        if (i < wv) off += wsum[i];
    int p0 = off + isc - s;
    int p1 = p0 + tot.x;
    int p2 = p1 + tot.y;
    int p3 = p2 + tot.z;
    if (idx < N_NODES) {
        row_ptr[idx + 0] = p0; dinv[idx + 0] = rsqrtf(1.f + (float)tot.x);
        row_ptr[idx + 1] = p1; dinv[idx + 1] = rsqrtf(1.f + (float)tot.y);
        row_ptr[idx + 2] = p2; dinv[idx + 2] = rsqrtf(1.f + (float)tot.z);
        row_ptr[idx + 3] = p3; dinv[idx + 3] = rsqrtf(1.f + (float)tot.w);
        int4 run = make_int4(p0, p1, p2, p3);
        #pragma unroll
        for (int q = 0; q < 4; ++q) {
            *(int4*)&cursor4[q * N_NODES + idx] = run;
            run.x += vq[q].x; run.y += vq[q].y;
            run.z += vq[q].z; run.w += vq[q].w;
        }
    }
    if (b == 0 && t == 0) row_ptr[N_NODES] = N_EDGES;
}

__global__ void k_fill(const int* __restrict__ row, const int* __restrict__ col,
                       int* __restrict__ cursor4, int* __restrict__ csr_src) {
    int i = (blockIdx.x * 256 + threadIdx.x) * 2;
    if (i < N_EDGES) {
        int2 c = *(const int2*)&col[i];
        int2 r = *(const int2*)&row[i];
        int p0 = atomicAdd(&cursor4[(i & 3) * N_NODES + c.x], 1);
        csr_src[p0] = r.x;
        int p1 = atomicAdd(&cursor4[((i + 1) & 3) * N_NODES + c.y], 1);
        csr_src[p1] = r.y;
    }
}

// ============ MFMA GEMM: yb_blk = bf16(dinv[r] * (x @ W)), COLUMN-BLOCKED ====
// Counted-vmcnt double-buffer (T3/T4): R10's dbuf failed because __syncthreads
// drains vmcnt(0) every step. Here: raw s_barrier + per-wave s_waitcnt vmcnt(6)
// -> tile k+2's 6 loads stay in flight across the barrier; loads lead compute
// by 2 phases (~600-1000cy ~= HBM latency). BK=32, 48KB LDS (2 bufs), 4 waves.
// Staging swizzles (R10, quarter-wave rule):
//  A rows 128B/8 slots: stored slot s of row r = logical s^(r&7).
//  B rows  64B/4 slots: stored slot s of row r = logical s^((r>>1)&3).
__launch_bounds__(256)
__global__ void k_gemm(const float* __restrict__ A,            // [N_NODES,512] fp32
                       const unsigned short* __restrict__ Wt,  // [256,512] bf16
                       const float* __restrict__ dinv,
                       unsigned short* __restrict__ yb)        // [8][N_NODES][32] bf16
{
    __shared__ __align__(16) float          As[2 * 128 * 32];   // 32 KB
    __shared__ __align__(16) unsigned short Bs[2 * 128 * 32];   // 16 KB

    // bijective XCD swizzle (m204)
    int orig = blockIdx.x;
    int xcd = orig % 8, pos = orig / 8;
    int wg = (xcd < GEMM_R) ? xcd * (GEMM_Q + 1) + pos
                            : GEMM_R * (GEMM_Q + 1) + (xcd - GEMM_R) * GEMM_Q + pos;
    const int nt = wg & 1;
    const int mt = wg >> 1;
    const int m0 = mt * 128;
    const int n0 = nt * 128;

    const int t  = threadIdx.x;
    const int w  = t >> 6;
    const int l  = t & 63;
    const int wm = (w >> 1) * 64;
    const int wn = (w & 1) * 64;
    const int lr = l & 15;
    const int lk = l >> 4;

    // A staging: 4 GLDs/wave; GLD i covers LDS rows w*32+i*8+(l>>3),
    // stored slot l&7 <- source slot (l&7)^(l>>3)
    size_t aoff[4];
    #pragma unroll
    for (int i = 0; i < 4; ++i) {
        int r = m0 + w * 32 + i * 8 + (l >> 3);
        if (r >= N_NODES) r = 0;                 // tail clamp; outputs guarded
        aoff[i] = (size_t)r * D_IN + ((l & 7) ^ (l >> 3)) * 4;   // float units
    }
    // B staging: 2 GLDs/wave; GLD i covers rows w*32+i*16+(l>>2),
    // stored slot l&3 <- source slot (l&3)^((l>>3)&3)
    size_t boff[2];
    #pragma unroll
    for (int i = 0; i < 2; ++i) {
        int r = n0 + w * 32 + i * 16 + (l >> 2);
        boff[i] = (size_t)r * D_IN + ((l & 3) ^ ((l >> 3) & 3)) * 8;   // bf16 units
    }

    f32x4 acc[4][4] = {};

    #define STAGE(buf, kk)                                                       \
        do {                                                                     \
            char* ab = (char*)As + (buf) * 16384 + w * 4096;                     \
            char* bb = (char*)Bs + (buf) * 8192  + w * 2048;                     \
            _Pragma("unroll")                                                    \
            for (int i = 0; i < 4; ++i) GLD16(&A[aoff[i] + (kk)], ab + i * 1024);\
            _Pragma("unroll")                                                    \
            for (int i = 0; i < 2; ++i) GLD16(&Wt[boff[i] + (kk)], bb + i * 1024);\
        } while (0)

    #define COMPUTE(buf)                                                         \
        do {                                                                     \
            const char* abase = (const char*)As + (buf) * 16384;                 \
            const char* bbase = (const char*)Bs + (buf) * 8192;                  \
            s8v af[4], bfr[4];                                                   \
            _Pragma("unroll")                                                    \
            for (int f = 0; f < 4; ++f) {                                        \
                int row = wm + f * 16 + lr;            /* row&7 == lr&7 */       \
                int s0  = (2 * lk) ^ (lr & 7);                                   \
                const char* pr = abase + row * 128;                              \
                float4 x0 = *(const float4*)(pr + s0 * 16);                      \
                float4 x1 = *(const float4*)(pr + (s0 ^ 1) * 16);                \
                union { s8v v; unsigned short h[8]; } u;                         \
                u.h[0] = bf16b(x0.x); u.h[1] = bf16b(x0.y);                      \
                u.h[2] = bf16b(x0.z); u.h[3] = bf16b(x0.w);                      \
                u.h[4] = bf16b(x1.x); u.h[5] = bf16b(x1.y);                      \
                u.h[6] = bf16b(x1.z); u.h[7] = bf16b(x1.w);                      \
                af[f] = u.v;                                                     \
            }                                                                    \
            _Pragma("unroll")                                                    \
            for (int f = 0; f < 4; ++f) {                                        \
                int row = wn + f * 16 + lr;        /* (row>>1)&3 == (lr>>1)&3 */ \
                int s   = lk ^ ((lr >> 1) & 3);                                  \
                bfr[f] = *(const s8v*)(bbase + row * 64 + s * 16);               \
            }                                                                    \
            _Pragma("unroll")                                                    \
            for (int fm = 0; fm < 4; ++fm)                                       \
                _Pragma("unroll")                                                \
                for (int fn = 0; fn < 4; ++fn)                                   \
                    acc[fm][fn] = __builtin_amdgcn_mfma_f32_16x16x32_bf16(       \
                        af[fm], bfr[fn], acc[fm][fn], 0, 0, 0);                  \
        } while (0)

    // prologue: 2 tiles in flight, wait only for tile 0
    STAGE(0, 0);
    STAGE(1, 32);
    asm volatile("s_waitcnt vmcnt(6)" ::: "memory");
    __builtin_amdgcn_s_barrier();

    #pragma unroll 1
    for (int tk = 0; tk < 14; ++tk) {
        COMPUTE(tk & 1);
        __builtin_amdgcn_s_barrier();            // all reads of buf tk&1 done
        STAGE(tk & 1, (tk + 2) * 32);            // overwrite with tile tk+2
        asm volatile("s_waitcnt vmcnt(6)" ::: "memory");   // tile tk+1 landed
        __builtin_amdgcn_s_barrier();            // publish tile tk+1
    }
    COMPUTE(0);                                  // tk = 14
    __builtin_amdgcn_s_barrier();
    asm volatile("s_waitcnt vmcnt(0)" ::: "memory");       // tile 15 landed
    __builtin_amdgcn_s_barrier();
    COMPUTE(1);                                  // tk = 15

    #undef STAGE
    #undef COMPUTE

    #pragma unroll
    for (int fm = 0; fm < 4; ++fm) {
        #pragma unroll
        for (int j = 0; j < 4; ++j) {
            int row = m0 + wm + fm * 16 + lk * 4 + j;
            if (row < N_NODES) {
                float s = dinv[row];
                #pragma unroll
                for (int fn = 0; fn < 4; ++fn) {
                    int col = n0 + wn + fn * 16 + lr;
                    size_t off = (size_t)(col >> 5) * (N_NODES * 32)
                               + (size_t)row * 32 + (col & 31);
                    yb[off] = bf16b(acc[fm][fn][j] * s);
                }
            }
        }
    }
}

// ============ gather (column-partitioned) — EXACT round-16 kernel (best:
// 61.2us, FETCH 60MB). slice = blockIdx%8 keeps each XCD in its 3.2MB
// L2-resident column slice. 4-lane groups, group = one target, lane owns one
// 16B col-slot; NO cross-lane reduction. Rounds of 4 edges in flight.
__device__ __forceinline__ void add8(float* acc, uint4 q) {
    unsigned x;
    x = q.x; acc[0] += bflo(x); acc[1] += bfhi(x);
    x = q.y; acc[2] += bflo(x); acc[3] += bfhi(x);
    x = q.z; acc[4] += bflo(x); acc[5] += bfhi(x);
    x = q.w; acc[6] += bflo(x); acc[7] += bfhi(x);
}

__launch_bounds__(256)
__global__ void k_gather(const int* __restrict__ row_ptr, const int* __restrict__ csr_src,
                         const unsigned short* __restrict__ yb,   // [8][N_NODES][32]
                         const float* __restrict__ dinv,
                         const float* __restrict__ bias, float* __restrict__ out)
{
    const int s     = blockIdx.x & 7;          // slice -> XCD (dispatch %8)
    const int chunk = blockIdx.x >> 3;
    const int g     = threadIdx.x >> 2;        // group 0..63 = target
    const int cs    = threadIdx.x & 3;         // 16B col-slot within slice
    const int c     = chunk * 64 + g;
    if (c >= N_NODES) return;

    const uint4* t4 = (const uint4*)(yb + (size_t)s * N_NODES * 32);  // 4 uint4/node

    float acc[8] = {0.f,0.f,0.f,0.f,0.f,0.f,0.f,0.f};

    const int e0 = row_ptr[c];
    const int e1 = row_ptr[c + 1];
    for (int i = e0; i < e1; i += 4) {
        int idx[4];
        #pragma unroll
        for (int j = 0; j < 4; ++j) {
            int p = i + j;
            idx[j] = csr_src[p < e1 ? p : e1 - 1];   // clamp: L1-hot re-read
        }
        uint4 v[4];
        #pragma unroll
        for (int j = 0; j < 4; ++j) v[j] = t4[(size_t)idx[j] * 4 + cs];
        #pragma unroll
        for (int j = 0; j < 4; ++j)
            if (i + j < e1) add8(acc, v[j]);         // group-uniform predicate
    }

    add8(acc, t4[(size_t)c * 4 + cs]);               // self-loop term

    const float sc = dinv[c];
    const int colb = s * 32 + cs * 8;
    float4 b0 = *(const float4*)&bias[colb];
    float4 b1 = *(const float4*)&bias[colb + 4];
    float4 o0, o1;
    o0.x = fmaxf(fmaf(acc[0], sc, b0.x), 0.f);
    o0.y = fmaxf(fmaf(acc[1], sc, b0.y), 0.f);
    o0.z = fmaxf(fmaf(acc[2], sc, b0.z), 0.f);
    o0.w = fmaxf(fmaf(acc[3], sc, b0.w), 0.f);
    o1.x = fmaxf(fmaf(acc[4], sc, b1.x), 0.f);
    o1.y = fmaxf(fmaf(acc[5], sc, b1.y), 0.f);
    o1.z = fmaxf(fmaf(acc[6], sc, b1.z), 0.f);
    o1.w = fmaxf(fmaf(acc[7], sc, b1.w), 0.f);
    float* dst = &out[(size_t)c * D_OUT + colb];
    *(float4*)dst       = o0;
    *(float4*)(dst + 4) = o1;
}

extern "C" void kernel_launch(void* const* d_in, const int* in_sizes, int n_in,
                              void* d_out, int out_size, void* d_ws, size_t ws_size,
                              hipStream_t stream) {
    const float* x   = (const float*)d_in[0];
    const int*   ei  = (const int*)d_in[1];
    const float* W   = (const float*)d_in[2];
    const float* b   = (const float*)d_in[3];
    float*       out = (float*)d_out;

    const int* row = ei;
    const int* col = ei + N_EDGES;

    char* p = (char*)d_ws;
    unsigned short* yb = (unsigned short*)p;  p += (size_t)N_NODES * D_OUT * 2;   // 25.6 MB
    unsigned short* Wt = (unsigned short*)p;  p += (size_t)D_OUT * D_IN * 2;      // 256 KB
    int*   csr_src = (int*)p;                 p += (size_t)N_EDGES * 4;           // 3.2 MB
    int*   cnt4    = (int*)p;                 p += (size_t)4 * N_NODES * 4;       // 800 KB
    int*   row_ptr = (int*)p;                 p += (size_t)(N_NODES + 4) * 4;
    int*   cursor4 = (int*)p;                 p += (size_t)4 * N_NODES * 4;       // 800 KB
    float* dinv    = (float*)p;               p += (size_t)N_NODES * 4;
    int*   bsum    = (int*)p;                 p += (size_t)NBLK_SCAN * 4;

    k_wt   <<<D_IN, D_OUT, 0, stream>>>(W, Wt, cnt4);   // also zeroes cnt4
    k_count<<<(N_EDGES / 2 + 255) / 256, 256, 0, stream>>>(col, cnt4);
    k_scan1<<<NBLK_SCAN, 256, 0, stream>>>(cnt4, bsum);
    k_scan3<<<NBLK_SCAN, 256, 0, stream>>>(cnt4, bsum, row_ptr, dinv, cursor4);
    k_fill <<<(N_EDGES / 2 + 255) / 256, 256, 0, stream>>>(row, col, cursor4, csr_src);

    k_gemm<<<GEMM_NWG, 256, 0, stream>>>(x, Wt, dinv, yb);

    k_gather<<<GATH_CHUNKS * 8, 256, 0, stream>>>(row_ptr, csr_src, yb, dinv, b, out);
}